// Round 4
// baseline (585.064 us; speedup 1.0000x reference)
//
#include <hip/hip_runtime.h>
#include <math.h>

#define B 16
#define N 4096
#define EPSF 1e-6f

__device__ __forceinline__ float waveReduceSum(float v) {
#pragma unroll
    for (int m = 32; m > 0; m >>= 1) v += __shfl_xor(v, m, 64);
    return v;
}

__device__ __forceinline__ void leaky3(float px, float py, float pz,
                                       float dx, float dy, float dz, float s,
                                       float& ox, float& oy, float& oz) {
    float dotr = px * dx + py * dy + pz * dz;
    float dsq = dx * dx + dy * dy + dz * dz;
    float dot = s * dotr;
    float coef = (dot >= 0.f) ? 0.f : (dot / (dsq + EPSF));
    ox = s * px - coef * dx;
    oy = s * py - coef * dy;
    oz = s * pz - coef * dz;
}

// Block-reduce NV per-thread f32 values -> one f64 atomicAdd per value per block.
template <int NV>
__device__ __forceinline__ void block_stats(float (&sv)[NV], float* red,
                                            double* gstats) {
    const int wid = threadIdx.x >> 6, lane = threadIdx.x & 63;
#pragma unroll
    for (int v = 0; v < NV; ++v) {
        float r = waveReduceSum(sv[v]);
        if (lane == 0) red[wid * NV + v] = r;
    }
    __syncthreads();
    if (threadIdx.x < NV) {
        float s = red[threadIdx.x] + red[NV + threadIdx.x] +
                  red[2 * NV + threadIdx.x] + red[3 * NV + threadIdx.x];
        atomicAdd(&gstats[threadIdx.x], (double)s);
    }
}

__device__ __forceinline__ void mk_muisd(const double* st, int cnt, double M,
                                         float* smu, float* sisd) {
    const int i = threadIdx.x;
    if (i < cnt) {
        double m = st[i] / M;
        double v = st[cnt + i] / M - m * m;
        smu[i] = (float)m;
        sisd[i] = (float)(1.0 / sqrt(v + 1e-5));
    }
}

struct Feat {
    float cx, cy, cz, e0x, e0y, e0z, e2x, e2y, e2z;
};

__device__ __forceinline__ Feat make_feat(const float* __restrict__ pc,
                                          const int* __restrict__ nbr, int tid) {
    const int b = tid >> 12, n = tid & (N - 1);
    const float* base = pc + (size_t)b * (3 * N);
    Feat f;
    f.cx = base[3 * n];
    f.cy = base[3 * n + 1];
    f.cz = base[3 * n + 2];
    const int jn = nbr[tid];
    float nx = base[3 * jn], ny = base[3 * jn + 1], nz = base[3 * jn + 2];
    f.e0x = nx - f.cx;
    f.e0y = ny - f.cy;
    f.e0z = nz - f.cz;
    f.e2x = ny * f.cz - nz * f.cy;
    f.e2y = nz * f.cx - nx * f.cz;
    f.e2z = nx * f.cy - ny * f.cx;
    return f;
}

__device__ __forceinline__ void l0_apply(const Feat& f, const float* wf0,
                                         const float* wd0, const float* g,
                                         const float* bb, const float* mu,
                                         const float* isd, float x[21][3]) {
#pragma unroll
    for (int o = 0; o < 21; ++o) {
        float w0 = wf0[3 * o], w1 = wf0[3 * o + 1], w2 = wf0[3 * o + 2];
        float u0 = wd0[3 * o], u1 = wd0[3 * o + 1], u2 = wd0[3 * o + 2];
        // self neighbor: e0 = 0, cross = 0 exactly -> p = w1*c, d = u1*c
        float pSx = w1 * f.cx, pSy = w1 * f.cy, pSz = w1 * f.cz;
        float nS = sqrtf(pSx * pSx + pSy * pSy + pSz * pSz) + EPSF;
        float sS = ((nS - mu[o]) * isd[o] * g[o] + bb[o]) / nS;
        float oSx, oSy, oSz;
        leaky3(pSx, pSy, pSz, u1 * f.cx, u1 * f.cy, u1 * f.cz, sS, oSx, oSy, oSz);
        // nearest neighbor
        float px = w0 * f.e0x + w1 * f.cx + w2 * f.e2x;
        float py = w0 * f.e0y + w1 * f.cy + w2 * f.e2y;
        float pz = w0 * f.e0z + w1 * f.cz + w2 * f.e2z;
        float dx = u0 * f.e0x + u1 * f.cx + u2 * f.e2x;
        float dy = u0 * f.e0y + u1 * f.cy + u2 * f.e2y;
        float dz = u0 * f.e0z + u1 * f.cz + u2 * f.e2z;
        float nN = sqrtf(px * px + py * py + pz * pz) + EPSF;
        float sN = ((nN - mu[o]) * isd[o] * g[o] + bb[o]) / nN;
        float oNx, oNy, oNz;
        leaky3(px, py, pz, dx, dy, dz, sN, oNx, oNy, oNz);
        x[o][0] = 0.5f * (oSx + oNx);
        x[o][1] = 0.5f * (oSy + oNy);
        x[o][2] = 0.5f * (oSz + oNz);
    }
}

__device__ __forceinline__ void l1_apply(float x[21][3], const float* wf1,
                                         const float* wd1, const float* g,
                                         const float* bb, const float* mu,
                                         const float* isd) {
    float nx[21][3];
#pragma unroll
    for (int o = 0; o < 21; ++o) {
        float px = 0.f, py = 0.f, pz = 0.f, dx = 0.f, dy = 0.f, dz = 0.f;
#pragma unroll
        for (int c = 0; c < 21; ++c) {
            float w = wf1[o * 21 + c], u = wd1[o * 21 + c];
            px += w * x[c][0]; py += w * x[c][1]; pz += w * x[c][2];
            dx += u * x[c][0]; dy += u * x[c][1]; dz += u * x[c][2];
        }
        float nn = sqrtf(px * px + py * py + pz * pz) + EPSF;
        float s = ((nn - mu[o]) * isd[o] * g[o] + bb[o]) / nn;
        leaky3(px, py, pz, dx, dy, dz, s, nx[o][0], nx[o][1], nx[o][2]);
    }
#pragma unroll
    for (int o = 0; o < 21; ++o) {
        x[o][0] = nx[o][0]; x[o][1] = nx[o][1]; x[o][2] = nx[o][2];
    }
}

__device__ __forceinline__ void bn1_apply(float x[21][3], const float* g,
                                          const float* bb, const float* mu,
                                          const float* isd) {
#pragma unroll
    for (int c = 0; c < 21; ++c) {
        float nn = sqrtf(x[c][0] * x[c][0] + x[c][1] * x[c][1] +
                         x[c][2] * x[c][2]) + EPSF;
        float sc = ((nn - mu[c]) * isd[c] * g[c] + bb[c]) / nn;
        x[c][0] *= sc; x[c][1] *= sc; x[c][2] *= sc;
    }
}

// ---------------- K1: nearest other point -------------------------------------------
// f32 scan with monotone proxy  q.x - |x|^2/2  (argmax == argmax of -|q-x|^2),
// butterfly merge keeping top-2, then exact f64 re-score of the two candidates.
#define QW 8
__global__ __launch_bounds__(256) void k_knn(const float* __restrict__ pc,
                                             int* __restrict__ nbrbest) {
    __shared__ float sx[N], sy[N], sz[N];
    const int b = blockIdx.x >> 7;             // 128 blocks per batch
    const int qblk = (blockIdx.x & 127) * 32;  // 32 queries per block
    const float* base = pc + (size_t)b * (N * 3);
    for (int j = threadIdx.x; j < N; j += 256) {
        sx[j] = base[3 * j + 0];
        sy[j] = base[3 * j + 1];
        sz[j] = base[3 * j + 2];
    }
    __syncthreads();
    const int wid = threadIdx.x >> 6, lane = threadIdx.x & 63;
    const int q0 = qblk + wid * QW;
    float qx[QW], qy[QW], qz[QW], bv[QW];
    int bi[QW];
#pragma unroll
    for (int q = 0; q < QW; ++q) {
        qx[q] = sx[q0 + q];
        qy[q] = sy[q0 + q];
        qz[q] = sz[q0 + q];
        bv[q] = -3.0e38f;
        bi[q] = 0;
    }
#pragma unroll 4
    for (int ch = 0; ch < N / 64; ++ch) {
        const int j = ch * 64 + lane;
        const float xd = sx[j], yd = sy[j], zd = sz[j];
        const float nr2h = -0.5f * (xd * xd + yd * yd + zd * zd);
#pragma unroll
        for (int q = 0; q < QW; ++q) {
            float pd = fmaf(qx[q], xd, fmaf(qy[q], yd, fmaf(qz[q], zd, nr2h)));
            bool upd = (pd > bv[q]) && (j != q0 + q);
            bv[q] = upd ? pd : bv[q];
            bi[q] = upd ? j : bi[q];
        }
    }
#pragma unroll
    for (int q = 0; q < QW; ++q) {
        // butterfly merge keeping top-2 (value desc, tie -> lower index)
        float a0v = bv[q], a1v = -3.0e38f;
        int a0i = bi[q], a1i = 0x7fffffff;
#pragma unroll
        for (int m = 1; m < 64; m <<= 1) {
            float b0v = __shfl_xor(a0v, m, 64), b1v = __shfl_xor(a1v, m, 64);
            int b0i = __shfl_xor(a0i, m, 64), b1i = __shfl_xor(a1i, m, 64);
            bool bf = (b0v > a0v) || (b0v == a0v && b0i < a0i);
            float c0v = bf ? a0v : b0v;  // loser of the head comparison
            int c0i = bf ? a0i : b0i;
            float c1v = bf ? b1v : a1v;  // winner's runner-up
            int c1i = bf ? b1i : a1i;
            a0v = bf ? b0v : a0v;
            a0i = bf ? b0i : a0i;
            bool cf = (c0v > c1v) || (c0v == c1v && c0i < c1i);
            a1v = cf ? c0v : c1v;
            a1i = cf ? c0i : c1i;
        }
        // exact f64 re-score of the two candidates (diff form)
        const int i0 = a0i, i1 = a1i;
        double dxa = (double)qx[q] - (double)sx[i0];
        double dya = (double)qy[q] - (double)sy[i0];
        double dza = (double)qz[q] - (double)sz[i0];
        double d0 = dxa * dxa + dya * dya + dza * dza;
        double dxb = (double)qx[q] - (double)sx[i1];
        double dyb = (double)qy[q] - (double)sy[i1];
        double dzb = (double)qz[q] - (double)sz[i1];
        double d1 = dxb * dxb + dyb * dyb + dzb * dzb;
        bool take1 = (d1 < d0) || (d1 == d0 && i1 < i0);
        int best = take1 ? i1 : i0;
        if (lane == 0) nbrbest[(size_t)b * N + q0 + q] = best;
    }
}

// ---------------- K2: layer0 BN stats ----------------------------------------------
__global__ __launch_bounds__(256) void k_st0(const float* __restrict__ pc,
                                             const int* __restrict__ nbr,
                                             const float* __restrict__ Wf0,
                                             double* __restrict__ st0) {
    __shared__ float wf0[63], red[168];
    if (threadIdx.x < 63) wf0[threadIdx.x] = Wf0[threadIdx.x];
    __syncthreads();
    const int tid = blockIdx.x * 256 + threadIdx.x;
    Feat f = make_feat(pc, nbr, tid);
    float sv[42];
#pragma unroll
    for (int o = 0; o < 21; ++o) {
        float w0 = wf0[3 * o], w1 = wf0[3 * o + 1], w2 = wf0[3 * o + 2];
        float pSx = w1 * f.cx, pSy = w1 * f.cy, pSz = w1 * f.cz;
        float nS = sqrtf(pSx * pSx + pSy * pSy + pSz * pSz) + EPSF;
        float px = w0 * f.e0x + w1 * f.cx + w2 * f.e2x;
        float py = w0 * f.e0y + w1 * f.cy + w2 * f.e2y;
        float pz = w0 * f.e0z + w1 * f.cz + w2 * f.e2z;
        float nN = sqrtf(px * px + py * py + pz * pz) + EPSF;
        sv[o] = nS + nN;
        sv[21 + o] = nS * nS + nN * nN;
    }
    block_stats<42>(sv, red, st0);
}

// ---------------- K3: layer1 BN stats ----------------------------------------------
__global__ __launch_bounds__(256) void k_st1(
    const float* __restrict__ pc, const int* __restrict__ nbr,
    const float* __restrict__ Wf0, const float* __restrict__ Wd0,
    const float* __restrict__ g0, const float* __restrict__ b0,
    const float* __restrict__ Wf1, const double* __restrict__ st0,
    double* __restrict__ st1) {
    __shared__ float wf0[63], wd0[63], wf1[441];
    __shared__ float g0s[21], b0s[21], mu0[21], isd0[21], red[168];
    if (threadIdx.x < 63) { wf0[threadIdx.x] = Wf0[threadIdx.x]; wd0[threadIdx.x] = Wd0[threadIdx.x]; }
    for (int i = threadIdx.x; i < 441; i += 256) wf1[i] = Wf1[i];
    if (threadIdx.x < 21) { g0s[threadIdx.x] = g0[threadIdx.x]; b0s[threadIdx.x] = b0[threadIdx.x]; }
    mk_muisd(st0, 21, (double)B * N * 2.0, mu0, isd0);
    __syncthreads();
    const int tid = blockIdx.x * 256 + threadIdx.x;
    Feat f = make_feat(pc, nbr, tid);
    float x[21][3];
    l0_apply(f, wf0, wd0, g0s, b0s, mu0, isd0, x);
    float sv[42];
#pragma unroll
    for (int o = 0; o < 21; ++o) {
        float px = 0.f, py = 0.f, pz = 0.f;
#pragma unroll
        for (int c = 0; c < 21; ++c) {
            float w = wf1[o * 21 + c];
            px += w * x[c][0]; py += w * x[c][1]; pz += w * x[c][2];
        }
        float nn = sqrtf(px * px + py * py + pz * pz) + EPSF;
        sv[o] = nn;
        sv[21 + o] = nn * nn;
    }
    block_stats<42>(sv, red, st1);
}

// ---------------- K4: bn1 stats (norms of layer1 output) ---------------------------
__global__ __launch_bounds__(256) void k_stB(
    const float* __restrict__ pc, const int* __restrict__ nbr,
    const float* __restrict__ Wf0, const float* __restrict__ Wd0,
    const float* __restrict__ g0, const float* __restrict__ b0,
    const float* __restrict__ Wf1, const float* __restrict__ Wd1,
    const float* __restrict__ g1, const float* __restrict__ b1,
    const double* __restrict__ st0, const double* __restrict__ st1,
    double* __restrict__ stB) {
    __shared__ float wf0[63], wd0[63], wf1[441], wd1[441];
    __shared__ float g0s[21], b0s[21], g1s[21], b1s[21];
    __shared__ float mu0[21], isd0[21], mu1[21], isd1[21], red[168];
    if (threadIdx.x < 63) { wf0[threadIdx.x] = Wf0[threadIdx.x]; wd0[threadIdx.x] = Wd0[threadIdx.x]; }
    for (int i = threadIdx.x; i < 441; i += 256) { wf1[i] = Wf1[i]; wd1[i] = Wd1[i]; }
    if (threadIdx.x < 21) {
        g0s[threadIdx.x] = g0[threadIdx.x]; b0s[threadIdx.x] = b0[threadIdx.x];
        g1s[threadIdx.x] = g1[threadIdx.x]; b1s[threadIdx.x] = b1[threadIdx.x];
    }
    mk_muisd(st0, 21, (double)B * N * 2.0, mu0, isd0);
    mk_muisd(st1, 21, (double)B * N, mu1, isd1);
    __syncthreads();
    const int tid = blockIdx.x * 256 + threadIdx.x;
    Feat f = make_feat(pc, nbr, tid);
    float x[21][3];
    l0_apply(f, wf0, wd0, g0s, b0s, mu0, isd0, x);
    l1_apply(x, wf1, wd1, g1s, b1s, mu1, isd1);
    float sv[42];
#pragma unroll
    for (int c = 0; c < 21; ++c) {
        float nn = sqrtf(x[c][0] * x[c][0] + x[c][1] * x[c][1] +
                         x[c][2] * x[c][2]) + EPSF;
        sv[c] = nn;
        sv[21 + c] = nn * nn;
    }
    block_stats<42>(sv, red, stB);
}

// ---------------- K5: layer2 BN stats ----------------------------------------------
__global__ __launch_bounds__(256) void k_st2(
    const float* __restrict__ pc, const int* __restrict__ nbr,
    const float* __restrict__ Wf0, const float* __restrict__ Wd0,
    const float* __restrict__ g0, const float* __restrict__ b0,
    const float* __restrict__ Wf1, const float* __restrict__ Wd1,
    const float* __restrict__ g1, const float* __restrict__ b1,
    const float* __restrict__ gbn1, const float* __restrict__ bbn1,
    const float* __restrict__ Wf2, const double* __restrict__ st0,
    const double* __restrict__ st1, const double* __restrict__ stB,
    double* __restrict__ st2) {
    __shared__ float wf0[63], wd0[63], wf1[441], wd1[441], wf2[63];
    __shared__ float g0s[21], b0s[21], g1s[21], b1s[21], gBs[21], bBs[21];
    __shared__ float mu0[21], isd0[21], mu1[21], isd1[21], muB[21], isdB[21], red[168];
    if (threadIdx.x < 63) {
        wf0[threadIdx.x] = Wf0[threadIdx.x]; wd0[threadIdx.x] = Wd0[threadIdx.x];
        wf2[threadIdx.x] = Wf2[threadIdx.x];
    }
    for (int i = threadIdx.x; i < 441; i += 256) { wf1[i] = Wf1[i]; wd1[i] = Wd1[i]; }
    if (threadIdx.x < 21) {
        g0s[threadIdx.x] = g0[threadIdx.x]; b0s[threadIdx.x] = b0[threadIdx.x];
        g1s[threadIdx.x] = g1[threadIdx.x]; b1s[threadIdx.x] = b1[threadIdx.x];
        gBs[threadIdx.x] = gbn1[threadIdx.x]; bBs[threadIdx.x] = bbn1[threadIdx.x];
    }
    mk_muisd(st0, 21, (double)B * N * 2.0, mu0, isd0);
    mk_muisd(st1, 21, (double)B * N, mu1, isd1);
    mk_muisd(stB, 21, (double)B * N, muB, isdB);
    __syncthreads();
    const int tid = blockIdx.x * 256 + threadIdx.x;
    Feat f = make_feat(pc, nbr, tid);
    float x[21][3];
    l0_apply(f, wf0, wd0, g0s, b0s, mu0, isd0, x);
    l1_apply(x, wf1, wd1, g1s, b1s, mu1, isd1);
    bn1_apply(x, gBs, bBs, muB, isdB);
    float sv[6];
#pragma unroll
    for (int o = 0; o < 3; ++o) {
        float px = 0.f, py = 0.f, pz = 0.f;
#pragma unroll
        for (int c = 0; c < 21; ++c) {
            float w = wf2[o * 21 + c];
            px += w * x[c][0]; py += w * x[c][1]; pz += w * x[c][2];
        }
        float nn = sqrtf(px * px + py * py + pz * pz) + EPSF;
        sv[o] = nn;
        sv[3 + o] = nn * nn;
    }
    block_stats<6>(sv, red, st2);
}

// ---------------- K6: layer2 apply + per-batch accumulation ------------------------
__global__ __launch_bounds__(256) void k_acc(
    const float* __restrict__ pc, const int* __restrict__ nbr,
    const float* __restrict__ Wf0, const float* __restrict__ Wd0,
    const float* __restrict__ g0, const float* __restrict__ b0,
    const float* __restrict__ Wf1, const float* __restrict__ Wd1,
    const float* __restrict__ g1, const float* __restrict__ b1,
    const float* __restrict__ gbn1, const float* __restrict__ bbn1,
    const float* __restrict__ Wf2, const float* __restrict__ Wd2,
    const float* __restrict__ g2, const float* __restrict__ b2,
    const double* __restrict__ st0, const double* __restrict__ st1,
    const double* __restrict__ stB, const double* __restrict__ st2,
    double* __restrict__ acc) {
    __shared__ float wf0[63], wd0[63], wf1[441], wd1[441], wf2[63], wd2[63];
    __shared__ float g0s[21], b0s[21], g1s[21], b1s[21], gBs[21], bBs[21], g2s[3], b2s[3];
    __shared__ float mu0[21], isd0[21], mu1[21], isd1[21], muB[21], isdB[21], mu2[3], isd2[3];
    __shared__ float red[168];
    if (threadIdx.x < 63) {
        wf0[threadIdx.x] = Wf0[threadIdx.x]; wd0[threadIdx.x] = Wd0[threadIdx.x];
        wf2[threadIdx.x] = Wf2[threadIdx.x]; wd2[threadIdx.x] = Wd2[threadIdx.x];
    }
    for (int i = threadIdx.x; i < 441; i += 256) { wf1[i] = Wf1[i]; wd1[i] = Wd1[i]; }
    if (threadIdx.x < 21) {
        g0s[threadIdx.x] = g0[threadIdx.x]; b0s[threadIdx.x] = b0[threadIdx.x];
        g1s[threadIdx.x] = g1[threadIdx.x]; b1s[threadIdx.x] = b1[threadIdx.x];
        gBs[threadIdx.x] = gbn1[threadIdx.x]; bBs[threadIdx.x] = bbn1[threadIdx.x];
    }
    if (threadIdx.x < 3) { g2s[threadIdx.x] = g2[threadIdx.x]; b2s[threadIdx.x] = b2[threadIdx.x]; }
    mk_muisd(st0, 21, (double)B * N * 2.0, mu0, isd0);
    mk_muisd(st1, 21, (double)B * N, mu1, isd1);
    mk_muisd(stB, 21, (double)B * N, muB, isdB);
    mk_muisd(st2, 3, (double)B * N, mu2, isd2);
    __syncthreads();
    const int tid = blockIdx.x * 256 + threadIdx.x;
    Feat f = make_feat(pc, nbr, tid);
    float x[21][3];
    l0_apply(f, wf0, wd0, g0s, b0s, mu0, isd0, x);
    l1_apply(x, wf1, wd1, g1s, b1s, mu1, isd1);
    bn1_apply(x, gBs, bBs, muB, isdB);
    float sv[9];
#pragma unroll
    for (int o = 0; o < 3; ++o) {
        float px = 0.f, py = 0.f, pz = 0.f, dx = 0.f, dy = 0.f, dz = 0.f;
#pragma unroll
        for (int c = 0; c < 21; ++c) {
            float w = wf2[o * 21 + c], u = wd2[o * 21 + c];
            px += w * x[c][0]; py += w * x[c][1]; pz += w * x[c][2];
            dx += u * x[c][0]; dy += u * x[c][1]; dz += u * x[c][2];
        }
        float nn = sqrtf(px * px + py * py + pz * pz) + EPSF;
        float s = ((nn - mu2[o]) * isd2[o] * g2s[o] + b2s[o]) / nn;
        leaky3(px, py, pz, dx, dy, dz, s, sv[3 * o], sv[3 * o + 1], sv[3 * o + 2]);
    }
    const int bb_ = blockIdx.x >> 4;
    block_stats<9>(sv, red, acc + bb_ * 9);
}

// ---------------- K7: finalize ------------------------------------------------------
__global__ void k_fin(const double* __restrict__ acc, float* __restrict__ out) {
    if (threadIdx.x < B * 9)
        out[threadIdx.x] = (float)(acc[threadIdx.x] * (1.0 / (double)N));
}

extern "C" void kernel_launch(void* const* d_in, const int* in_sizes, int n_in,
                              void* d_out, int out_size, void* d_ws, size_t ws_size,
                              hipStream_t stream) {
    const float* pc = (const float*)d_in[0];
    const float* Wf0 = (const float*)d_in[1];
    const float* Wd0 = (const float*)d_in[2];
    const float* g0 = (const float*)d_in[3];
    const float* b0 = (const float*)d_in[4];
    const float* Wf1 = (const float*)d_in[5];
    const float* Wd1 = (const float*)d_in[6];
    const float* g1 = (const float*)d_in[7];
    const float* b1 = (const float*)d_in[8];
    const float* gbn1 = (const float*)d_in[9];
    const float* bbn1 = (const float*)d_in[10];
    const float* Wf2 = (const float*)d_in[11];
    const float* Wd2 = (const float*)d_in[12];
    const float* g2 = (const float*)d_in[13];
    const float* b2 = (const float*)d_in[14];
    float* out = (float*)d_out;

    char* ws = (char*)d_ws;
    double* st0 = (double*)ws;          // 42
    double* st1 = st0 + 42;             // 42
    double* stB = st1 + 42;             // 42
    double* st2 = stB + 42;             // 6
    double* acc = st2 + 6;              // 144  (total 276 doubles < 4096 B)
    int* nbrbest = (int*)(ws + 4096);   // B*N ints

    hipMemsetAsync(d_ws, 0, 4096, stream);

    k_knn<<<B * (N / 32), 256, 0, stream>>>(pc, nbrbest);
    k_st0<<<B * N / 256, 256, 0, stream>>>(pc, nbrbest, Wf0, st0);
    k_st1<<<B * N / 256, 256, 0, stream>>>(pc, nbrbest, Wf0, Wd0, g0, b0, Wf1, st0, st1);
    k_stB<<<B * N / 256, 256, 0, stream>>>(pc, nbrbest, Wf0, Wd0, g0, b0, Wf1, Wd1,
                                           g1, b1, st0, st1, stB);
    k_st2<<<B * N / 256, 256, 0, stream>>>(pc, nbrbest, Wf0, Wd0, g0, b0, Wf1, Wd1,
                                           g1, b1, gbn1, bbn1, Wf2, st0, st1, stB, st2);
    k_acc<<<B * N / 256, 256, 0, stream>>>(pc, nbrbest, Wf0, Wd0, g0, b0, Wf1, Wd1,
                                           g1, b1, gbn1, bbn1, Wf2, Wd2, g2, b2,
                                           st0, st1, stB, st2, acc);
    k_fin<<<1, 256, 0, stream>>>(acc, out);
}

// Round 5
// 295.955 us; speedup vs baseline: 1.9769x; 1.9769x over previous
//
#include <hip/hip_runtime.h>
#include <math.h>

#define B 16
#define N 4096
#define NPTS (B * N)   // 65536
#define EPSF 1e-6f
#define S8(i) ((i) * 8)  // 64B-padded double slot

__device__ __forceinline__ float waveReduceSum(float v) {
#pragma unroll
    for (int m = 32; m > 0; m >>= 1) v += __shfl_xor(v, m, 64);
    return v;
}

__device__ __forceinline__ void leaky3(float px, float py, float pz,
                                       float dx, float dy, float dz, float s,
                                       float& ox, float& oy, float& oz) {
    float dotr = px * dx + py * dy + pz * dz;
    float dsq = dx * dx + dy * dy + dz * dz;
    float dot = s * dotr;
    float coef = (dot >= 0.f) ? 0.f : (dot / (dsq + EPSF));
    ox = s * px - coef * dx;
    oy = s * py - coef * dy;
    oz = s * pz - coef * dz;
}

// stats stored padded: sum at st[S8(i)], sumsq at st[S8(cnt+i)]
__device__ __forceinline__ void mk_muisd(const double* st, int cnt, double M,
                                         float* smu, float* sisd) {
    const int i = threadIdx.x;
    if (i < cnt) {
        double m = st[S8(i)] / M;
        double v = st[S8(cnt + i)] / M - m * m;
        smu[i] = (float)m;
        sisd[i] = (float)(1.0 / sqrt(v + 1e-5));
    }
}

// ---------------- K1: nearest other point (unchanged from round 4) -----------------
#define QW 8
__global__ __launch_bounds__(256) void k_knn(const float* __restrict__ pc,
                                             int* __restrict__ nbrbest) {
    __shared__ float sx[N], sy[N], sz[N];
    const int b = blockIdx.x >> 7;
    const int qblk = (blockIdx.x & 127) * 32;
    const float* base = pc + (size_t)b * (N * 3);
    for (int j = threadIdx.x; j < N; j += 256) {
        sx[j] = base[3 * j + 0];
        sy[j] = base[3 * j + 1];
        sz[j] = base[3 * j + 2];
    }
    __syncthreads();
    const int wid = threadIdx.x >> 6, lane = threadIdx.x & 63;
    const int q0 = qblk + wid * QW;
    float qx[QW], qy[QW], qz[QW], bv[QW];
    int bi[QW];
#pragma unroll
    for (int q = 0; q < QW; ++q) {
        qx[q] = sx[q0 + q];
        qy[q] = sy[q0 + q];
        qz[q] = sz[q0 + q];
        bv[q] = -3.0e38f;
        bi[q] = 0;
    }
#pragma unroll 4
    for (int ch = 0; ch < N / 64; ++ch) {
        const int j = ch * 64 + lane;
        const float xd = sx[j], yd = sy[j], zd = sz[j];
        const float nr2h = -0.5f * (xd * xd + yd * yd + zd * zd);
#pragma unroll
        for (int q = 0; q < QW; ++q) {
            float pd = fmaf(qx[q], xd, fmaf(qy[q], yd, fmaf(qz[q], zd, nr2h)));
            bool upd = (pd > bv[q]) && (j != q0 + q);
            bv[q] = upd ? pd : bv[q];
            bi[q] = upd ? j : bi[q];
        }
    }
#pragma unroll
    for (int q = 0; q < QW; ++q) {
        float a0v = bv[q], a1v = -3.0e38f;
        int a0i = bi[q], a1i = 0x7fffffff;
#pragma unroll
        for (int m = 1; m < 64; m <<= 1) {
            float b0v = __shfl_xor(a0v, m, 64), b1v = __shfl_xor(a1v, m, 64);
            int b0i = __shfl_xor(a0i, m, 64), b1i = __shfl_xor(a1i, m, 64);
            bool bf = (b0v > a0v) || (b0v == a0v && b0i < a0i);
            float c0v = bf ? a0v : b0v;
            int c0i = bf ? a0i : b0i;
            float c1v = bf ? b1v : a1v;
            int c1i = bf ? b1i : a1i;
            a0v = bf ? b0v : a0v;
            a0i = bf ? b0i : a0i;
            bool cf = (c0v > c1v) || (c0v == c1v && c0i < c1i);
            a1v = cf ? c0v : c1v;
            a1i = cf ? c0i : c1i;
        }
        const int i0 = a0i, i1 = a1i;
        double dxa = (double)qx[q] - (double)sx[i0];
        double dya = (double)qy[q] - (double)sy[i0];
        double dza = (double)qz[q] - (double)sz[i0];
        double d0 = dxa * dxa + dya * dya + dza * dza;
        double dxb = (double)qx[q] - (double)sx[i1];
        double dyb = (double)qy[q] - (double)sy[i1];
        double dzb = (double)qz[q] - (double)sz[i1];
        double d1 = dxb * dxb + dyb * dyb + dzb * dzb;
        bool take1 = (d1 < d0) || (d1 == d0 && i1 < i0);
        int best = take1 ? i1 : i0;
        if (lane == 0) nbrbest[(size_t)b * N + q0 + q] = best;
    }
}

// Layout for all stage kernels: block = 64 points x 4 waves.
// wave w owns channel group w: channels [w*6, w*6+6) intersect [0,21).
// lane = point-within-tile; pid = blockIdx.x*64 + lane.

// ---------------- K2: layer0 BN stats ----------------------------------------------
__global__ __launch_bounds__(256) void k_st0(const float* __restrict__ pc,
                                             const int* __restrict__ nbr,
                                             const float* __restrict__ Wf0,
                                             double* __restrict__ st0) {
    __shared__ float wf0[63];
    if (threadIdx.x < 63) wf0[threadIdx.x] = Wf0[threadIdx.x];
    __syncthreads();
    const int lane = threadIdx.x & 63, grp = threadIdx.x >> 6;
    const int pid = blockIdx.x * 64 + lane;
    const int b = pid >> 12, n = pid & (N - 1);
    const float* base = pc + (size_t)b * (3 * N);
    const float cx = base[3 * n], cy = base[3 * n + 1], cz = base[3 * n + 2];
    const int jn = nbr[pid];
    const float nx = base[3 * jn], ny = base[3 * jn + 1], nz = base[3 * jn + 2];
    const float e0x = nx - cx, e0y = ny - cy, e0z = nz - cz;
    const float e2x = ny * cz - nz * cy;
    const float e2y = nz * cx - nx * cz;
    const float e2z = nx * cy - ny * cx;
    const int cbase = grp * 6;
    float sv1[6], sv2[6];
#pragma unroll
    for (int k = 0; k < 6; ++k) {
        const int c = cbase + k;
        const bool act = c < 21;
        const int cc = act ? c : 20;
        float w0 = wf0[3 * cc], w1 = wf0[3 * cc + 1], w2 = wf0[3 * cc + 2];
        float pSx = w1 * cx, pSy = w1 * cy, pSz = w1 * cz;
        float nS = sqrtf(pSx * pSx + pSy * pSy + pSz * pSz) + EPSF;
        float px = w0 * e0x + w1 * cx + w2 * e2x;
        float py = w0 * e0y + w1 * cy + w2 * e2y;
        float pz = w0 * e0z + w1 * cz + w2 * e2z;
        float nN = sqrtf(px * px + py * py + pz * pz) + EPSF;
        sv1[k] = act ? (nS + nN) : 0.f;
        sv2[k] = act ? (nS * nS + nN * nN) : 0.f;
    }
#pragma unroll
    for (int k = 0; k < 6; ++k) {
        float r1 = waveReduceSum(sv1[k]);
        float r2 = waveReduceSum(sv2[k]);
        const int c = cbase + k;
        if (lane == 0 && c < 21) {
            atomicAdd(&st0[S8(c)], (double)r1);
            atomicAdd(&st0[S8(21 + c)], (double)r2);
        }
    }
}

// ---------------- K3: layer0 apply -> xbuf (feature-major) -------------------------
__global__ __launch_bounds__(256) void k_l0(
    const float* __restrict__ pc, const int* __restrict__ nbr,
    const float* __restrict__ Wf0, const float* __restrict__ Wd0,
    const float* __restrict__ g0, const float* __restrict__ b0,
    const double* __restrict__ st0, float* __restrict__ xbuf) {
    __shared__ float wf0[63], wd0[63], gg[21], bb[21], mu[21], isd[21];
    if (threadIdx.x < 63) {
        wf0[threadIdx.x] = Wf0[threadIdx.x];
        wd0[threadIdx.x] = Wd0[threadIdx.x];
    }
    if (threadIdx.x < 21) {
        gg[threadIdx.x] = g0[threadIdx.x];
        bb[threadIdx.x] = b0[threadIdx.x];
    }
    mk_muisd(st0, 21, (double)B * N * 2.0, mu, isd);
    __syncthreads();
    const int lane = threadIdx.x & 63, grp = threadIdx.x >> 6;
    const int pid = blockIdx.x * 64 + lane;
    const int b = pid >> 12, n = pid & (N - 1);
    const float* base = pc + (size_t)b * (3 * N);
    const float cx = base[3 * n], cy = base[3 * n + 1], cz = base[3 * n + 2];
    const int jn = nbr[pid];
    const float nx = base[3 * jn], ny = base[3 * jn + 1], nz = base[3 * jn + 2];
    const float e0x = nx - cx, e0y = ny - cy, e0z = nz - cz;
    const float e2x = ny * cz - nz * cy;
    const float e2y = nz * cx - nx * cz;
    const float e2z = nx * cy - ny * cx;
    const int cbase = grp * 6;
#pragma unroll
    for (int k = 0; k < 6; ++k) {
        const int c = cbase + k;
        const bool act = c < 21;
        const int cc = act ? c : 20;
        float w0 = wf0[3 * cc], w1 = wf0[3 * cc + 1], w2 = wf0[3 * cc + 2];
        float u0 = wd0[3 * cc], u1 = wd0[3 * cc + 1], u2 = wd0[3 * cc + 2];
        // self neighbor
        float pSx = w1 * cx, pSy = w1 * cy, pSz = w1 * cz;
        float nS = sqrtf(pSx * pSx + pSy * pSy + pSz * pSz) + EPSF;
        float sS = ((nS - mu[cc]) * isd[cc] * gg[cc] + bb[cc]) / nS;
        float oSx, oSy, oSz;
        leaky3(pSx, pSy, pSz, u1 * cx, u1 * cy, u1 * cz, sS, oSx, oSy, oSz);
        // nearest neighbor
        float px = w0 * e0x + w1 * cx + w2 * e2x;
        float py = w0 * e0y + w1 * cy + w2 * e2y;
        float pz = w0 * e0z + w1 * cz + w2 * e2z;
        float dx = u0 * e0x + u1 * cx + u2 * e2x;
        float dy = u0 * e0y + u1 * cy + u2 * e2y;
        float dz = u0 * e0z + u1 * cz + u2 * e2z;
        float nN = sqrtf(px * px + py * py + pz * pz) + EPSF;
        float sN = ((nN - mu[cc]) * isd[cc] * gg[cc] + bb[cc]) / nN;
        float oNx, oNy, oNz;
        leaky3(px, py, pz, dx, dy, dz, sN, oNx, oNy, oNz);
        if (act) {
            xbuf[(size_t)(c * 3 + 0) * NPTS + pid] = 0.5f * (oSx + oNx);
            xbuf[(size_t)(c * 3 + 1) * NPTS + pid] = 0.5f * (oSy + oNy);
            xbuf[(size_t)(c * 3 + 2) * NPTS + pid] = 0.5f * (oSz + oNz);
        }
    }
}

// ---------------- K4: layer1 BN stats ----------------------------------------------
__global__ __launch_bounds__(256) void k_st1(const float* __restrict__ xbuf,
                                             const float* __restrict__ Wf1,
                                             double* __restrict__ st1) {
    __shared__ float wf1[441];
    for (int i = threadIdx.x; i < 441; i += 256) wf1[i] = Wf1[i];
    __syncthreads();
    const int lane = threadIdx.x & 63, grp = threadIdx.x >> 6;
    const int pid = blockIdx.x * 64 + lane;
    float x[63];
#pragma unroll
    for (int f = 0; f < 63; ++f) x[f] = xbuf[(size_t)f * NPTS + pid];
    const int cbase = grp * 6;
    float sv1[6], sv2[6];
#pragma unroll
    for (int k = 0; k < 6; ++k) {
        const int c = cbase + k;
        const bool act = c < 21;
        const int cc = act ? c : 20;
        float p0 = 0.f, p1 = 0.f, p2 = 0.f;
#pragma unroll
        for (int j = 0; j < 21; ++j) {
            float w = wf1[cc * 21 + j];
            p0 = fmaf(w, x[3 * j + 0], p0);
            p1 = fmaf(w, x[3 * j + 1], p1);
            p2 = fmaf(w, x[3 * j + 2], p2);
        }
        float nn = sqrtf(p0 * p0 + p1 * p1 + p2 * p2) + EPSF;
        sv1[k] = act ? nn : 0.f;
        sv2[k] = act ? nn * nn : 0.f;
    }
#pragma unroll
    for (int k = 0; k < 6; ++k) {
        float r1 = waveReduceSum(sv1[k]);
        float r2 = waveReduceSum(sv2[k]);
        const int c = cbase + k;
        if (lane == 0 && c < 21) {
            atomicAdd(&st1[S8(c)], (double)r1);
            atomicAdd(&st1[S8(21 + c)], (double)r2);
        }
    }
}

// ---------------- K5: layer1 apply (in-place x->y) + bn1 stats ---------------------
__global__ __launch_bounds__(256) void k_l1(
    float* __restrict__ xbuf, const float* __restrict__ Wf1,
    const float* __restrict__ Wd1, const float* __restrict__ g1,
    const float* __restrict__ b1, const double* __restrict__ st1,
    double* __restrict__ stB) {
    __shared__ float wf1[441], wd1[441], gg[21], bb[21], mu[21], isd[21];
    for (int i = threadIdx.x; i < 441; i += 256) {
        wf1[i] = Wf1[i];
        wd1[i] = Wd1[i];
    }
    if (threadIdx.x < 21) {
        gg[threadIdx.x] = g1[threadIdx.x];
        bb[threadIdx.x] = b1[threadIdx.x];
    }
    mk_muisd(st1, 21, (double)B * N, mu, isd);
    __syncthreads();
    const int lane = threadIdx.x & 63, grp = threadIdx.x >> 6;
    const int pid = blockIdx.x * 64 + lane;
    float x[63];
#pragma unroll
    for (int f = 0; f < 63; ++f) x[f] = xbuf[(size_t)f * NPTS + pid];
    __syncthreads();  // all reads done before any in-place write (block-local pids)
    const int cbase = grp * 6;
    float sv1[6], sv2[6];
#pragma unroll
    for (int k = 0; k < 6; ++k) {
        const int c = cbase + k;
        const bool act = c < 21;
        const int cc = act ? c : 20;
        float p0 = 0.f, p1 = 0.f, p2 = 0.f, d0 = 0.f, d1 = 0.f, d2 = 0.f;
#pragma unroll
        for (int j = 0; j < 21; ++j) {
            float w = wf1[cc * 21 + j], u = wd1[cc * 21 + j];
            p0 = fmaf(w, x[3 * j + 0], p0);
            p1 = fmaf(w, x[3 * j + 1], p1);
            p2 = fmaf(w, x[3 * j + 2], p2);
            d0 = fmaf(u, x[3 * j + 0], d0);
            d1 = fmaf(u, x[3 * j + 1], d1);
            d2 = fmaf(u, x[3 * j + 2], d2);
        }
        float nn = sqrtf(p0 * p0 + p1 * p1 + p2 * p2) + EPSF;
        float s = ((nn - mu[cc]) * isd[cc] * gg[cc] + bb[cc]) / nn;
        float ox, oy, oz;
        leaky3(p0, p1, p2, d0, d1, d2, s, ox, oy, oz);
        float on = sqrtf(ox * ox + oy * oy + oz * oz) + EPSF;
        sv1[k] = act ? on : 0.f;
        sv2[k] = act ? on * on : 0.f;
        if (act) {
            xbuf[(size_t)(c * 3 + 0) * NPTS + pid] = ox;
            xbuf[(size_t)(c * 3 + 1) * NPTS + pid] = oy;
            xbuf[(size_t)(c * 3 + 2) * NPTS + pid] = oz;
        }
    }
#pragma unroll
    for (int k = 0; k < 6; ++k) {
        float r1 = waveReduceSum(sv1[k]);
        float r2 = waveReduceSum(sv2[k]);
        const int c = cbase + k;
        if (lane == 0 && c < 21) {
            atomicAdd(&stB[S8(c)], (double)r1);
            atomicAdd(&stB[S8(21 + c)], (double)r2);
        }
    }
}

// ---------------- K6: bn1 apply (in-place y->z) ------------------------------------
__global__ __launch_bounds__(256) void k_bn1(float* __restrict__ xbuf,
                                             const float* __restrict__ gbn,
                                             const float* __restrict__ bbn,
                                             const double* __restrict__ stB) {
    __shared__ float gg[21], bb[21], mu[21], isd[21];
    if (threadIdx.x < 21) {
        gg[threadIdx.x] = gbn[threadIdx.x];
        bb[threadIdx.x] = bbn[threadIdx.x];
    }
    mk_muisd(stB, 21, (double)B * N, mu, isd);
    __syncthreads();
    const int lane = threadIdx.x & 63, grp = threadIdx.x >> 6;
    const int pid = blockIdx.x * 64 + lane;
    const int cbase = grp * 6;
#pragma unroll
    for (int k = 0; k < 6; ++k) {
        const int c = cbase + k;
        if (c >= 21) break;
        float y0 = xbuf[(size_t)(c * 3 + 0) * NPTS + pid];
        float y1 = xbuf[(size_t)(c * 3 + 1) * NPTS + pid];
        float y2 = xbuf[(size_t)(c * 3 + 2) * NPTS + pid];
        float nn = sqrtf(y0 * y0 + y1 * y1 + y2 * y2) + EPSF;
        float sc = ((nn - mu[c]) * isd[c] * gg[c] + bb[c]) / nn;
        xbuf[(size_t)(c * 3 + 0) * NPTS + pid] = sc * y0;
        xbuf[(size_t)(c * 3 + 1) * NPTS + pid] = sc * y1;
        xbuf[(size_t)(c * 3 + 2) * NPTS + pid] = sc * y2;
    }
}

// ---------------- K7: layer2 BN stats (3 channels; wave grp = channel) -------------
__global__ __launch_bounds__(256) void k_st2(const float* __restrict__ xbuf,
                                             const float* __restrict__ Wf2,
                                             double* __restrict__ st2) {
    __shared__ float wf2[63];
    if (threadIdx.x < 63) wf2[threadIdx.x] = Wf2[threadIdx.x];
    __syncthreads();
    const int lane = threadIdx.x & 63, grp = threadIdx.x >> 6;
    if (grp >= 3) return;
    const int pid = blockIdx.x * 64 + lane;
    float x[63];
#pragma unroll
    for (int f = 0; f < 63; ++f) x[f] = xbuf[(size_t)f * NPTS + pid];
    float p0 = 0.f, p1 = 0.f, p2 = 0.f;
#pragma unroll
    for (int j = 0; j < 21; ++j) {
        float w = wf2[grp * 21 + j];
        p0 = fmaf(w, x[3 * j + 0], p0);
        p1 = fmaf(w, x[3 * j + 1], p1);
        p2 = fmaf(w, x[3 * j + 2], p2);
    }
    float nn = sqrtf(p0 * p0 + p1 * p1 + p2 * p2) + EPSF;
    float r1 = waveReduceSum(nn);
    float r2 = waveReduceSum(nn * nn);
    if (lane == 0) {
        atomicAdd(&st2[S8(grp)], (double)r1);
        atomicAdd(&st2[S8(3 + grp)], (double)r2);
    }
}

// ---------------- K8: layer2 apply + per-batch reduce ------------------------------
__global__ __launch_bounds__(256) void k_acc(
    const float* __restrict__ xbuf, const float* __restrict__ Wf2,
    const float* __restrict__ Wd2, const float* __restrict__ g2,
    const float* __restrict__ b2, const double* __restrict__ st2,
    double* __restrict__ acc) {
    __shared__ float wf2[63], wd2[63], gg[3], bb[3], mu[3], isd[3];
    if (threadIdx.x < 63) {
        wf2[threadIdx.x] = Wf2[threadIdx.x];
        wd2[threadIdx.x] = Wd2[threadIdx.x];
    }
    if (threadIdx.x < 3) {
        gg[threadIdx.x] = g2[threadIdx.x];
        bb[threadIdx.x] = b2[threadIdx.x];
    }
    mk_muisd(st2, 3, (double)B * N, mu, isd);
    __syncthreads();
    const int lane = threadIdx.x & 63, grp = threadIdx.x >> 6;
    if (grp >= 3) return;
    const int pid = blockIdx.x * 64 + lane;
    const int b = pid >> 12;
    float x[63];
#pragma unroll
    for (int f = 0; f < 63; ++f) x[f] = xbuf[(size_t)f * NPTS + pid];
    float p0 = 0.f, p1 = 0.f, p2 = 0.f, d0 = 0.f, d1 = 0.f, d2 = 0.f;
#pragma unroll
    for (int j = 0; j < 21; ++j) {
        float w = wf2[grp * 21 + j], u = wd2[grp * 21 + j];
        p0 = fmaf(w, x[3 * j + 0], p0);
        p1 = fmaf(w, x[3 * j + 1], p1);
        p2 = fmaf(w, x[3 * j + 2], p2);
        d0 = fmaf(u, x[3 * j + 0], d0);
        d1 = fmaf(u, x[3 * j + 1], d1);
        d2 = fmaf(u, x[3 * j + 2], d2);
    }
    float nn = sqrtf(p0 * p0 + p1 * p1 + p2 * p2) + EPSF;
    float s = ((nn - mu[grp]) * isd[grp] * gg[grp] + bb[grp]) / nn;
    float ox, oy, oz;
    leaky3(p0, p1, p2, d0, d1, d2, s, ox, oy, oz);
    float rx = waveReduceSum(ox);
    float ry = waveReduceSum(oy);
    float rz = waveReduceSum(oz);
    if (lane == 0) {
        atomicAdd(&acc[S8(b * 9 + grp * 3 + 0)], (double)rx);
        atomicAdd(&acc[S8(b * 9 + grp * 3 + 1)], (double)ry);
        atomicAdd(&acc[S8(b * 9 + grp * 3 + 2)], (double)rz);
    }
}

// ---------------- K9: finalize ------------------------------------------------------
__global__ void k_fin(const double* __restrict__ acc, float* __restrict__ out) {
    if (threadIdx.x < B * 9)
        out[threadIdx.x] = (float)(acc[S8(threadIdx.x)] * (1.0 / (double)N));
}

extern "C" void kernel_launch(void* const* d_in, const int* in_sizes, int n_in,
                              void* d_out, int out_size, void* d_ws, size_t ws_size,
                              hipStream_t stream) {
    const float* pc = (const float*)d_in[0];
    const float* Wf0 = (const float*)d_in[1];
    const float* Wd0 = (const float*)d_in[2];
    const float* g0 = (const float*)d_in[3];
    const float* b0 = (const float*)d_in[4];
    const float* Wf1 = (const float*)d_in[5];
    const float* Wd1 = (const float*)d_in[6];
    const float* g1 = (const float*)d_in[7];
    const float* b1 = (const float*)d_in[8];
    const float* gbn1 = (const float*)d_in[9];
    const float* bbn1 = (const float*)d_in[10];
    const float* Wf2 = (const float*)d_in[11];
    const float* Wd2 = (const float*)d_in[12];
    const float* g2 = (const float*)d_in[13];
    const float* b2 = (const float*)d_in[14];
    float* out = (float*)d_out;

    char* ws = (char*)d_ws;
    double* gws = (double*)ws;
    double* st0 = gws;          // slots [0,336)   (42 values, 64B stride)
    double* st1 = gws + 336;    // [336,672)
    double* stB = gws + 672;    // [672,1008)
    double* st2 = gws + 1008;   // [1008,1056)  (6 values)
    double* acc = gws + 1056;   // [1056,2208)  (144 values)
    int* nbrbest = (int*)(ws + 32768);            // B*N ints = 256KB
    float* xbuf = (float*)(ws + 32768 + 262144);  // 63*NPTS floats = 16.5MB

    hipMemsetAsync(d_ws, 0, 2208 * 8, stream);

    k_knn<<<B * (N / 32), 256, 0, stream>>>(pc, nbrbest);
    k_st0<<<NPTS / 64, 256, 0, stream>>>(pc, nbrbest, Wf0, st0);
    k_l0<<<NPTS / 64, 256, 0, stream>>>(pc, nbrbest, Wf0, Wd0, g0, b0, st0, xbuf);
    k_st1<<<NPTS / 64, 256, 0, stream>>>(xbuf, Wf1, st1);
    k_l1<<<NPTS / 64, 256, 0, stream>>>(xbuf, Wf1, Wd1, g1, b1, st1, stB);
    k_bn1<<<NPTS / 64, 256, 0, stream>>>(xbuf, gbn1, bbn1, stB);
    k_st2<<<NPTS / 64, 256, 0, stream>>>(xbuf, Wf2, st2);
    k_acc<<<NPTS / 64, 256, 0, stream>>>(xbuf, Wf2, Wd2, g2, b2, st2, acc);
    k_fin<<<1, 256, 0, stream>>>(acc, out);
}